// Round 2
// baseline (1193.026 us; speedup 1.0000x reference)
//
#include <hip/hip_runtime.h>
#include <hip/hip_bf16.h>

// Problem constants: N_NODES=50000, N_EDGES=800000, MAX_NEI=16, D=256
#define D_DIM 256
#define MAX_NEI 16

// ---------------- Kernel 1: support = input @ W^T + b_lin (fp32 GEMM) ----------------
// C[m][o] = sum_d A[m][d] * W[o][d]  (NT dot-of-rows, both row-major contiguous K)
// Tile 128x128, TK=32, 256 threads, 8x8 micro-tile.
// Thread (tx,ty): rows m0+ty*8..+7, cols {n0+tx*4..+3} U {n0+64+tx*4..+3}.
//   A-frag read: 4 addrs/wave, 16-lane broadcast -> conflict-free.
//   B-frag read: 16 lanes x 16B contiguous (256B) -> 2-way alias -> free (m136).
#define TM 128
#define TN 128
#define TK 32
#define LDS_PAD 4  // row stride 132 floats = 528 B, 16B-aligned for float4 LDS reads

__global__ __launch_bounds__(256) void gemm_support(
    const float* __restrict__ A,     // [M, 256]
    const float* __restrict__ W,     // [256, 256]
    const float* __restrict__ blin,  // [256]
    float* __restrict__ S,           // [M, 256] out
    int M)
{
    __shared__ float As[TK][TM + LDS_PAD];
    __shared__ float Ws[TK][TN + LDS_PAD];

    const int tid = threadIdx.x;
    const int tx = tid & 15;        // col group 0..15
    const int ty = tid >> 4;        // row group 0..15
    const int m0 = blockIdx.x * TM;
    const int n0 = blockIdx.y * TN;

    // staging: 8 threads cover one row's 32-float K-slab as one float4 each
    const int kk = (tid & 7) * 4;   // k offset within tile
    const int rr = tid >> 3;        // row 0..31, 4 passes of 32

    float acc[8][8];
    #pragma unroll
    for (int i = 0; i < 8; ++i)
        #pragma unroll
        for (int j = 0; j < 8; ++j) acc[i][j] = 0.f;

    for (int k0 = 0; k0 < D_DIM; k0 += TK) {
        #pragma unroll
        for (int p = 0; p < 4; ++p) {
            int m = m0 + rr + 32 * p;
            int ms = m < M ? m : (M - 1);           // clamp; masked at store
            const float4 v = *(const float4*)(A + (size_t)ms * D_DIM + k0 + kk);
            As[kk + 0][rr + 32 * p] = v.x;
            As[kk + 1][rr + 32 * p] = v.y;
            As[kk + 2][rr + 32 * p] = v.z;
            As[kk + 3][rr + 32 * p] = v.w;
        }
        #pragma unroll
        for (int p = 0; p < 4; ++p) {
            int o = n0 + rr + 32 * p;               // N=256, never OOB
            const float4 v = *(const float4*)(W + (size_t)o * D_DIM + k0 + kk);
            Ws[kk + 0][rr + 32 * p] = v.x;
            Ws[kk + 1][rr + 32 * p] = v.y;
            Ws[kk + 2][rr + 32 * p] = v.z;
            Ws[kk + 3][rr + 32 * p] = v.w;
        }
        __syncthreads();

        #pragma unroll
        for (int k = 0; k < TK; ++k) {
            float a[8], b[8];
            *(float4*)&a[0] = *(const float4*)&As[k][ty * 8 + 0];
            *(float4*)&a[4] = *(const float4*)&As[k][ty * 8 + 4];
            *(float4*)&b[0] = *(const float4*)&Ws[k][tx * 4 + 0];        // cols tx*4..+3
            *(float4*)&b[4] = *(const float4*)&Ws[k][64 + tx * 4 + 0];   // cols 64+tx*4..+3
            #pragma unroll
            for (int i = 0; i < 8; ++i)
                #pragma unroll
                for (int j = 0; j < 8; ++j)
                    acc[i][j] += a[i] * b[j];
        }
        __syncthreads();
    }

    // epilogue: + b_lin, store two float4s per row
    const int c0 = n0 + tx * 4;
    const int c1 = c0 + 64;
    const float4 b0 = *(const float4*)(blin + c0);
    const float4 b1 = *(const float4*)(blin + c1);
    #pragma unroll
    for (int i = 0; i < 8; ++i) {
        int m = m0 + ty * 8 + i;
        if (m < M) {
            float4 v0, v1;
            v0.x = acc[i][0] + b0.x; v0.y = acc[i][1] + b0.y;
            v0.z = acc[i][2] + b0.z; v0.w = acc[i][3] + b0.w;
            v1.x = acc[i][4] + b1.x; v1.y = acc[i][5] + b1.y;
            v1.z = acc[i][6] + b1.z; v1.w = acc[i][7] + b1.w;
            *(float4*)(S + (size_t)m * D_DIM + c0) = v0;
            *(float4*)(S + (size_t)m * D_DIM + c1) = v1;
        }
    }
}

// ---------------- Kernel 2: gather, multiply, reduce over K, tanh+bias ----------------
// One wave per node; lane i holds float4 at col 4*i -> one 1KB row per load instr.
// Indices are wave-uniform -> readfirstlane forces SGPR base addressing (saddr form).
// Chunks of 4 neighbors bound VGPR pressure to ~8 float4 loads in flight.
__device__ __forceinline__ float fast_tanh(float x) {
    // algebraically exact: 1 - 2/(e^{2x}+1); saturates cleanly at both ends
    float e = __expf(2.0f * x);
    return 1.0f - 2.0f / (e + 1.0f);
}

__global__ __launch_bounds__(256) void gather_msg(
    const float* __restrict__ S,       // [N, 256] support
    const float* __restrict__ fedges,  // [E, 256]
    const int*   __restrict__ a2a,     // [N, 16]
    const int*   __restrict__ n2e,     // [N, 16]
    const float* __restrict__ bias,    // [256]
    float* __restrict__ out,           // [N, 256]
    int N)
{
    const int node = blockIdx.x * 4 + (threadIdx.x >> 6);
    const int lane = threadIdx.x & 63;
    if (node >= N) return;
    const int off = lane * 4;

    // Load 16+16 indices via int4 (same addr across lanes -> broadcast loads)
    int ja[MAX_NEI], je[MAX_NEI];
    {
        const int4* pa = (const int4*)(a2a + (size_t)node * MAX_NEI);
        const int4* pe = (const int4*)(n2e + (size_t)node * MAX_NEI);
        #pragma unroll
        for (int q = 0; q < 4; ++q) {
            const int4 va = pa[q];
            const int4 ve = pe[q];
            ja[4 * q + 0] = va.x; ja[4 * q + 1] = va.y;
            ja[4 * q + 2] = va.z; ja[4 * q + 3] = va.w;
            je[4 * q + 0] = ve.x; je[4 * q + 1] = ve.y;
            je[4 * q + 2] = ve.z; je[4 * q + 3] = ve.w;
        }
    }

    float4 acc = make_float4(0.f, 0.f, 0.f, 0.f);
    #pragma unroll
    for (int c = 0; c < MAX_NEI; c += 4) {
        // force wave-uniform indices into SGPRs -> scalar-base vector loads
        const int a0 = __builtin_amdgcn_readfirstlane(ja[c + 0]);
        const int a1 = __builtin_amdgcn_readfirstlane(ja[c + 1]);
        const int a2 = __builtin_amdgcn_readfirstlane(ja[c + 2]);
        const int a3 = __builtin_amdgcn_readfirstlane(ja[c + 3]);
        const int e0 = __builtin_amdgcn_readfirstlane(je[c + 0]);
        const int e1 = __builtin_amdgcn_readfirstlane(je[c + 1]);
        const int e2 = __builtin_amdgcn_readfirstlane(je[c + 2]);
        const int e3 = __builtin_amdgcn_readfirstlane(je[c + 3]);

        const float4 s0 = *(const float4*)(S + (size_t)a0 * D_DIM + off);
        const float4 s1 = *(const float4*)(S + (size_t)a1 * D_DIM + off);
        const float4 s2 = *(const float4*)(S + (size_t)a2 * D_DIM + off);
        const float4 s3 = *(const float4*)(S + (size_t)a3 * D_DIM + off);
        const float4 f0 = *(const float4*)(fedges + (size_t)e0 * D_DIM + off);
        const float4 f1 = *(const float4*)(fedges + (size_t)e1 * D_DIM + off);
        const float4 f2 = *(const float4*)(fedges + (size_t)e2 * D_DIM + off);
        const float4 f3 = *(const float4*)(fedges + (size_t)e3 * D_DIM + off);

        acc.x += s0.x * f0.x; acc.y += s0.y * f0.y; acc.z += s0.z * f0.z; acc.w += s0.w * f0.w;
        acc.x += s1.x * f1.x; acc.y += s1.y * f1.y; acc.z += s1.z * f1.z; acc.w += s1.w * f1.w;
        acc.x += s2.x * f2.x; acc.y += s2.y * f2.y; acc.z += s2.z * f2.z; acc.w += s2.w * f2.w;
        acc.x += s3.x * f3.x; acc.y += s3.y * f3.y; acc.z += s3.z * f3.z; acc.w += s3.w * f3.w;
    }

    const float4 bv = *(const float4*)(bias + off);
    float4 r;
    r.x = fast_tanh(acc.x) + bv.x;
    r.y = fast_tanh(acc.y) + bv.y;
    r.z = fast_tanh(acc.z) + bv.z;
    r.w = fast_tanh(acc.w) + bv.w;
    *(float4*)(out + (size_t)node * D_DIM + off) = r;
}

extern "C" void kernel_launch(void* const* d_in, const int* in_sizes, int n_in,
                              void* d_out, int out_size, void* d_ws, size_t ws_size,
                              hipStream_t stream) {
    const float* input_features = (const float*)d_in[0];  // [N, 256]
    const float* fedges         = (const float*)d_in[1];  // [E, 256]
    const int*   a2a            = (const int*)d_in[2];    // [N, 16]
    const int*   n2e            = (const int*)d_in[3];    // [N, 16]
    const float* W              = (const float*)d_in[4];  // [256, 256]
    const float* b_lin          = (const float*)d_in[5];  // [256]
    const float* bias           = (const float*)d_in[6];  // [256]
    float* out = (float*)d_out;

    const int N = in_sizes[0] / D_DIM;   // 50000
    float* support = (float*)d_ws;       // N*256*4 = 51.2 MB scratch

    dim3 g1((N + TM - 1) / TM, D_DIM / TN);
    gemm_support<<<g1, 256, 0, stream>>>(input_features, W, b_lin, support, N);

    dim3 g2((N + 3) / 4);
    gather_msg<<<g2, 256, 0, stream>>>(support, fedges, a2a, n2e, bias, out, N);
}